// Round 16
// baseline (4047.397 us; speedup 1.0000x reference)
//
#include <hip/hip_runtime.h>
#include <hip/hip_bf16.h>
#include <math.h>

// ---------------- problem constants ----------------
#define BB 64
#define CC 3
#define HH 256
#define WW 256
#define PP 16
#define DD 1024
#define DEPTH 10
#define HEADS 2
#define DHD 64
#define MLPD 256
#define INNER 128
#define NCLS 16
#define NT 288
#define PDIM 768
#define SCALE_ 0.125f
#define MROWS 18432          // BB*NT

typedef unsigned short u16;
typedef __attribute__((ext_vector_type(4))) int   i32x4;
typedef __attribute__((ext_vector_type(4))) float f32x4;

// ---------------- helpers ----------------
__device__ __forceinline__ float gelu_f(float x) {
    return 0.5f * x * (1.0f + erff(x * 0.70710678118654752f));
}

__device__ __forceinline__ u16 f2bf_rne(float x) {
    unsigned u = __float_as_uint(x);
    unsigned r = u + 0x7FFFu + ((u >> 16) & 1u);
    return (u16)(r >> 16);
}
__device__ __forceinline__ void split_bf(float x, u16& h, u16& l) {
    h = f2bf_rne(x);
    float fh = __uint_as_float(((unsigned)h) << 16);
    l = f2bf_rne(x - fh);
}

__device__ __forceinline__ void mfma_bf16(f32x4& acc, i32x4 a, i32x4 b) {
    asm("v_mfma_f32_16x16x32_bf16 %0, %1, %2, %0" : "+v"(acc) : "v"(a), "v"(b));
}

__device__ __forceinline__ void gload16(const void* g, void* l) {
    __builtin_amdgcn_global_load_lds(
        (const __attribute__((address_space(1))) void*)g,
        (__attribute__((address_space(3))) void*)l, 16, 0, 0);
}

__device__ __forceinline__ float block_sum_1024(float v, float* red) {
    #pragma unroll
    for (int off = 32; off; off >>= 1) v += __shfl_xor(v, off);
    __syncthreads();
    if ((threadIdx.x & 63) == 0) red[threadIdx.x >> 6] = v;
    __syncthreads();
    return red[0] + red[1] + red[2] + red[3];
}

// LN-transform 8 consecutive elems and split to packed hi/lo bf16x8
__device__ __forceinline__ void ln_split8(float4 xa, float4 xb, float mean, float rstd,
                                          float4 sa, float4 sb, float4 ba, float4 b_b,
                                          i32x4& hi, i32x4& lo) {
    float v0 = (xa.x - mean) * rstd * sa.x + ba.x;
    float v1 = (xa.y - mean) * rstd * sa.y + ba.y;
    float v2 = (xa.z - mean) * rstd * sa.z + ba.z;
    float v3 = (xa.w - mean) * rstd * sa.w + ba.w;
    float v4 = (xb.x - mean) * rstd * sb.x + b_b.x;
    float v5 = (xb.y - mean) * rstd * sb.y + b_b.y;
    float v6 = (xb.z - mean) * rstd * sb.z + b_b.z;
    float v7 = (xb.w - mean) * rstd * sb.w + b_b.w;
    u16 h0,h1,h2,h3,h4,h5,h6,h7, l0,l1,l2,l3,l4,l5,l6,l7;
    split_bf(v0,h0,l0); split_bf(v1,h1,l1); split_bf(v2,h2,l2); split_bf(v3,h3,l3);
    split_bf(v4,h4,l4); split_bf(v5,h5,l5); split_bf(v6,h6,l6); split_bf(v7,h7,l7);
    hi[0] = h0 | (h1 << 16); hi[1] = h2 | (h3 << 16);
    hi[2] = h4 | (h5 << 16); hi[3] = h6 | (h7 << 16);
    lo[0] = l0 | (l1 << 16); lo[1] = l2 | (l3 << 16);
    lo[2] = l4 | (l5 << 16); lo[3] = l6 | (l7 << 16);
}

// ---------------- patch gather (split bf16 hi/lo) ----------------
__global__ __launch_bounds__(256)
void build_patches(const float* __restrict__ img, u16* __restrict__ Xh,
                   u16* __restrict__ Xl) {
    size_t e = (size_t)blockIdx.x * 256 + threadIdx.x;  // 64*256*768
    int pd = (int)(e % 768); size_t r = e / 768;
    int t  = (int)(r % 256); int b = (int)(r / 256);
    int c = pd % 3; int pp = pd / 3; int px = pp & 15, py = pp >> 4;
    int wp = t & 15, hp = t >> 4;
    float v = img[(((size_t)b * 3 + c) * 256 + hp * 16 + py) * 256 + wp * 16 + px];
    u16 h, l; split_bf(v, h, l);
    Xh[e] = h; Xl[e] = l;
}

// ---------------- finish embed + layer-0 LN stats ----------------
__global__ __launch_bounds__(256)
void finish_embed_stats(const float* __restrict__ clb, const float* __restrict__ pos,
                        float* __restrict__ X, float2* __restrict__ stats) {
    __shared__ float red[4];
    int row = blockIdx.x; int t = row % NT;
    int tid = threadIdx.x;
    size_t xi = (size_t)row * 1024 + tid * 4;
    float4 p = *(const float4*)&pos[(size_t)t * 1024 + tid * 4];
    float4 v;
    if (t < 16)        v = *(const float4*)&clb[t * 1024 + tid * 4];
    else if (t >= 272) v = *(const float4*)&clb[(t - 256) * 1024 + tid * 4];
    else               v = *(const float4*)&X[xi];
    v.x += p.x; v.y += p.y; v.z += p.z; v.w += p.w;
    *(float4*)&X[xi] = v;
    float s = v.x + v.y + v.z + v.w;
    float q = v.x*v.x + v.y*v.y + v.z*v.z + v.w*v.w;
    float st = block_sum_1024(s, red);
    float qt = block_sum_1024(q, red);
    if (tid == 0) stats[row] = make_float2(st, qt);
}

// ---------------- weight convert: W f32 [K][N] -> hi/lo bf16 [N][K] -------
__global__ __launch_bounds__(256)
void convert_wT(const float* __restrict__ W, u16* __restrict__ Wh,
                u16* __restrict__ Wl, int K, int N) {
    __shared__ float t[32][33];
    int n0 = blockIdx.x * 32, k0 = blockIdx.y * 32;
    int c = threadIdx.x & 31, r8 = threadIdx.x >> 5;
    #pragma unroll
    for (int rr = r8; rr < 32; rr += 8)
        t[rr][c] = W[(size_t)(k0 + rr) * N + n0 + c];
    __syncthreads();
    #pragma unroll
    for (int rr = r8; rr < 32; rr += 8) {
        float v = t[c][rr];
        u16 h, l; split_bf(v, h, l);
        size_t o = (size_t)(n0 + rr) * K + k0 + c;
        Wh[o] = h; Wl[o] = l;
    }
}

// ---------------- all-layer weight convert (one launch) ----------------
__global__ __launch_bounds__(256)
void bigconvert(const float* __restrict__ Wqkv, const float* __restrict__ Wo,
                const float* __restrict__ W1, const float* __restrict__ W2,
                u16* __restrict__ wbase) {
    __shared__ float t[32][33];
    int bid = blockIdx.x;
    int layer = bid >> 10, tt = bid & 1023;
    u16* lb = wbase + (size_t)layer * 2097152;
    const float* src; u16* dh; u16* dl; int K, N, tloc;
    if (tt < 384)      { tloc = tt;       src = Wqkv + (size_t)layer*393216; K = 1024; N = 384;  dh = lb;           dl = lb + 393216; }
    else if (tt < 512) { tloc = tt - 384; src = Wo   + (size_t)layer*131072; K = 128;  N = 1024; dh = lb + 786432;  dl = lb + 917504; }
    else if (tt < 768) { tloc = tt - 512; src = W1   + (size_t)layer*262144; K = 1024; N = 256;  dh = lb + 1048576; dl = lb + 1310720; }
    else               { tloc = tt - 768; src = W2   + (size_t)layer*262144; K = 256;  N = 1024; dh = lb + 1572864; dl = lb + 1835008; }
    int tn = N >> 5;
    int n0 = (tloc % tn) * 32, k0 = (tloc / tn) * 32;
    int c = threadIdx.x & 31, r8 = threadIdx.x >> 5;
    #pragma unroll
    for (int rr = r8; rr < 32; rr += 8)
        t[rr][c] = src[(size_t)(k0 + rr) * N + n0 + c];
    __syncthreads();
    #pragma unroll
    for (int rr = r8; rr < 32; rr += 8) {
        float v = t[c][rr];
        u16 h, l; split_bf(v, h, l);
        size_t o = (size_t)(n0 + rr) * K + k0 + c;
        dh[o] = h; dl[o] = l;
    }
}

// ---------------- bf16x3 MFMA GEMM (R13 champion: gload_lds + vec epi) ----
#define SOFF(reg, tile) (((reg) * 8 + (tile)) * 512)
template<int EPI, bool ROWMAP, bool ALN, bool PERM, bool STATS>
__global__ __launch_bounds__(256, 2)
void gemm_bf16x3(const u16* __restrict__ Ah, const u16* __restrict__ Al,
                 const u16* __restrict__ Bh, const u16* __restrict__ Bl,
                 const float* __restrict__ bias, float* __restrict__ out,
                 u16* __restrict__ outH, u16* __restrict__ outL,
                 const float* __restrict__ xsrc,
                 const float2* __restrict__ statsIn, int ncb,
                 float2* __restrict__ statsOut,
                 const float* __restrict__ lns, const float* __restrict__ lnb,
                 int M, int Nn, int K, int NTn, int mtq) {
    __shared__ u16 smem[16384];            // (Ah,Al,Bh,Bl) x 8 tiles x 1KB = 32KB
    const int tid = threadIdx.x;
    const int w = tid >> 6, lane = tid & 63;
    const int wr = w >> 1, wc = w & 1;
    const int bid = blockIdx.x;
    const int loc = bid >> 3;
    const int n_t = loc % NTn;
    const int m_t = (bid & 7) * mtq + loc / NTn;
    const int m0 = m_t << 7, n0 = n_t << 7;
    const int lr = lane & 15, lg = lane >> 4;

    const u16* gp[8];
    int lb[8];
    {
        size_t b0 = (size_t)(n0 + (2 * w) * 16 + lr) * K + lg * 8;
        size_t b1 = (size_t)(n0 + (2 * w + 1) * 16 + lr) * K + lg * 8;
        gp[4] = Bh + b0; gp[5] = Bh + b1; gp[6] = Bl + b0; gp[7] = Bl + b1;
        if (!ALN) {
            size_t a0 = (size_t)(m0 + (2 * w) * 16 + lr) * K + lg * 8;
            size_t a1 = (size_t)(m0 + (2 * w + 1) * 16 + lr) * K + lg * 8;
            gp[0] = Ah + a0; gp[1] = Ah + a1; gp[2] = Al + a0; gp[3] = Al + a1;
        }
        lb[0] = SOFF(0, 2 * w); lb[1] = SOFF(0, 2 * w + 1);
        lb[2] = SOFF(1, 2 * w); lb[3] = SOFF(1, 2 * w + 1);
        lb[4] = SOFF(2, 2 * w); lb[5] = SOFF(2, 2 * w + 1);
        lb[6] = SOFF(3, 2 * w); lb[7] = SOFF(3, 2 * w + 1);
    }

    float mean0 = 0.f, rstd0 = 0.f, mean1 = 0.f, rstd1 = 0.f;
    const float* xr0 = nullptr; const float* xr1 = nullptr;
    if (ALN) {
        int r0 = m0 + (2 * w) * 16 + lr;
        int r1 = r0 + 16;
        float s0 = 0.f, q0 = 0.f, s1 = 0.f, q1 = 0.f;
        for (int cb = 0; cb < ncb; cb++) {
            float2 a = statsIn[cb * M + r0]; s0 += a.x; q0 += a.y;
            float2 b = statsIn[cb * M + r1]; s1 += b.x; q1 += b.y;
        }
        mean0 = s0 * (1.0f / 1024.0f);
        rstd0 = rsqrtf(q0 * (1.0f / 1024.0f) - mean0 * mean0 + 1e-5f);
        mean1 = s1 * (1.0f / 1024.0f);
        rstd1 = rsqrtf(q1 * (1.0f / 1024.0f) - mean1 * mean1 + 1e-5f);
        xr0 = xsrc + (size_t)r0 * K + lg * 8;
        xr1 = xsrc + (size_t)r1 * K + lg * 8;
    }

    f32x4 acc[4][4];
    #pragma unroll
    for (int i = 0; i < 4; i++)
        #pragma unroll
        for (int j = 0; j < 4; j++) acc[i][j] = f32x4{0.f, 0.f, 0.f, 0.f};

    const int nks = K >> 5;
    const int lo8 = lane * 8;
    for (int ks = 0; ks < nks; ks++) {
        // ---- stage step ks into the single buffer ----
        if (ALN) {
            #pragma unroll
            for (int q = 4; q < 8; q++) { gload16(gp[q], &smem[lb[q]]); gp[q] += 32; }
            const int kofs = ks * 32;
            float4 xa0 = *(const float4*)(xr0 + kofs), xb0 = *(const float4*)(xr0 + kofs + 4);
            float4 xa1 = *(const float4*)(xr1 + kofs), xb1 = *(const float4*)(xr1 + kofs + 4);
            const int kn = kofs + lg * 8;
            float4 sa = *(const float4*)(lns + kn), sb = *(const float4*)(lns + kn + 4);
            float4 ba = *(const float4*)(lnb + kn), b_b = *(const float4*)(lnb + kn + 4);
            i32x4 hi0, lo0, hi1, lo1;
            ln_split8(xa0, xb0, mean0, rstd0, sa, sb, ba, b_b, hi0, lo0);
            ln_split8(xa1, xb1, mean1, rstd1, sa, sb, ba, b_b, hi1, lo1);
            *(i32x4*)&smem[lb[0] + lane * 8] = hi0;
            *(i32x4*)&smem[lb[1] + lane * 8] = hi1;
            *(i32x4*)&smem[lb[2] + lane * 8] = lo0;
            *(i32x4*)&smem[lb[3] + lane * 8] = lo1;
        } else {
            #pragma unroll
            for (int q = 0; q < 8; q++) { gload16(gp[q], &smem[lb[q]]); gp[q] += 32; }
        }
        __syncthreads();
        // ---- compute ----
        i32x4 a_h[4], a_l[4], b_h[4], b_l[4];
        #pragma unroll
        for (int i = 0; i < 4; i++) {
            a_h[i] = *(const i32x4*)&smem[SOFF(0, wr * 4 + i) + lo8];
            a_l[i] = *(const i32x4*)&smem[SOFF(1, wr * 4 + i) + lo8];
            b_h[i] = *(const i32x4*)&smem[SOFF(2, wc * 4 + i) + lo8];
            b_l[i] = *(const i32x4*)&smem[SOFF(3, wc * 4 + i) + lo8];
        }
        #pragma unroll
        for (int i = 0; i < 4; i++)
            #pragma unroll
            for (int j = 0; j < 4; j++) {
                mfma_bf16(acc[i][j], a_h[i], b_h[j]);
                mfma_bf16(acc[i][j], a_h[i], b_l[j]);
                mfma_bf16(acc[i][j], a_l[i], b_h[j]);
            }
        __syncthreads();
    }

    // ---- vectorized epilogue: stage acc -> LDS (f32), float4 IO ----
    float* lds_f = (float*)smem;
    #pragma unroll
    for (int h = 0; h < 2; h++) {
        __syncthreads();
        if (wr == h) {
            #pragma unroll
            for (int i = 0; i < 4; i++)
                #pragma unroll
                for (int j = 0; j < 4; j++)
                    #pragma unroll
                    for (int r = 0; r < 4; r++)
                        lds_f[(i * 16 + lg * 4 + r) * 128 + wc * 64 + j * 16 + lr]
                            = acc[i][j][r];
        }
        __syncthreads();
        #pragma unroll
        for (int k = 0; k < 8; k++) {
            int f = k * 256 + tid;
            int rloc = f >> 5;
            int c4 = f & 31;
            int row = m0 + h * 64 + rloc;
            int col = n0 + c4 * 4;
            float4 v = *(float4*)&lds_f[rloc * 128 + c4 * 4];
            if (EPI >= 1) {
                float4 bv = *(const float4*)&bias[col];
                v.x += bv.x; v.y += bv.y; v.z += bv.z; v.w += bv.w;
            }
            int orow = row;
            if (ROWMAP) orow = row + 16 + 32 * (row >> 8);
            if (PERM) {
                int bi = row / 288; int t1 = row - bi * 288;
                int hp = t1 / 18; int wp = t1 - hp * 18;
                orow = bi * 288 + wp * 16 + hp;
            }
            size_t oidx = (size_t)orow * Nn + col;
            if (EPI == 3) {
                ushort4 hv, lv;
                float g0 = gelu_f(v.x), g1 = gelu_f(v.y);
                float g2 = gelu_f(v.z), g3 = gelu_f(v.w);
                split_bf(g0, hv.x, lv.x); split_bf(g1, hv.y, lv.y);
                split_bf(g2, hv.z, lv.z); split_bf(g3, hv.w, lv.w);
                *(ushort4*)&outH[oidx] = hv;
                *(ushort4*)&outL[oidx] = lv;
            } else if (EPI == 2) {
                float4 rv = *(float4*)&out[oidx];
                v.x += rv.x; v.y += rv.y; v.z += rv.z; v.w += rv.w;
                *(float4*)&out[oidx] = v;
                if (STATS) {
                    float s = v.x + v.y + v.z + v.w;
                    float q = v.x*v.x + v.y*v.y + v.z*v.z + v.w*v.w;
                    #pragma unroll
                    for (int off = 1; off < 32; off <<= 1) {
                        s += __shfl_xor(s, off);
                        q += __shfl_xor(q, off);
                    }
                    if ((tid & 31) == 0)
                        statsOut[n_t * M + row] = make_float2(s, q);
                }
            } else {
                *(float4*)&out[oidx] = v;
            }
        }
    }
}

// ---------------- f32 GEMM (tiny cls matmuls, M=16) ----------
template<int EPI>
__global__ __launch_bounds__(256)
void gemm_f32(const float* __restrict__ A, const float* __restrict__ Wt,
              const float* __restrict__ bias, float* __restrict__ Cout,
              int M, int Nn, int K) {
    __shared__ float As[16][132];
    __shared__ float Bs[16][68];
    const int tid = threadIdx.x;
    const int m0 = blockIdx.y * 128;
    const int n0 = blockIdx.x * 64;
    const int ty = tid >> 4, tx = tid & 15;
    float acc[8][4];
    #pragma unroll
    for (int r = 0; r < 8; r++)
        #pragma unroll
        for (int c = 0; c < 4; c++) acc[r][c] = 0.0f;
    const int af4 = tid & 3;
    const int arow0 = tid >> 2;
    const int bcol = tid & 63, brow0 = tid >> 6;
    for (int k0 = 0; k0 < K; k0 += 16) {
        #pragma unroll
        for (int rr = 0; rr < 2; rr++) {
            int row = arow0 + rr * 64;
            int gm = m0 + row;
            float4 v = make_float4(0.f, 0.f, 0.f, 0.f);
            if (gm < M) v = *(const float4*)&A[(size_t)gm * K + k0 + af4 * 4];
            As[af4 * 4 + 0][row] = v.x; As[af4 * 4 + 1][row] = v.y;
            As[af4 * 4 + 2][row] = v.z; As[af4 * 4 + 3][row] = v.w;
        }
        #pragma unroll
        for (int rr = 0; rr < 4; rr++) {
            int krow = brow0 + rr * 4;
            Bs[krow][bcol] = Wt[(size_t)(k0 + krow) * Nn + n0 + bcol];
        }
        __syncthreads();
        #pragma unroll
        for (int kk = 0; kk < 16; kk++) {
            float4 a0 = *(const float4*)&As[kk][ty * 8];
            float4 a1 = *(const float4*)&As[kk][ty * 8 + 4];
            float4 b0 = *(const float4*)&Bs[kk][tx * 4];
            float ar[8] = {a0.x, a0.y, a0.z, a0.w, a1.x, a1.y, a1.z, a1.w};
            float bc[4] = {b0.x, b0.y, b0.z, b0.w};
            #pragma unroll
            for (int r = 0; r < 8; r++)
                #pragma unroll
                for (int c = 0; c < 4; c++)
                    acc[r][c] = fmaf(ar[r], bc[c], acc[r][c]);
        }
        __syncthreads();
    }
    float4 bv = make_float4(0.f, 0.f, 0.f, 0.f);
    if (EPI >= 1) bv = *(const float4*)&bias[n0 + tx * 4];
    #pragma unroll
    for (int r = 0; r < 8; r++) {
        int gm = m0 + ty * 8 + r;
        if (gm >= M) continue;
        float4 v = make_float4(acc[r][0], acc[r][1], acc[r][2], acc[r][3]);
        if (EPI >= 1) { v.x += bv.x; v.y += bv.y; v.z += bv.z; v.w += bv.w; }
        *(float4*)&Cout[(size_t)gm * Nn + n0 + tx * 4] = v;
    }
}

// ---------------- attention (flash-style, f32, float4 LDS) ----------------
// LDS-throughput rewrite: padded-68 rows (16B aligned), float4 staging and
// fragment reads (4x fewer LDS instrs, 2x bytes/cycle), conflict-free K-row
// mapping j = jg + 8*jj (bank starts 4*jg+d -> full 32-bank tiling), float4
// P/V reads, ushort4 stores. FMA order identical to scalar version.
__global__ __launch_bounds__(256)
void attn_kernel(const float* __restrict__ qkv, u16* __restrict__ Oh,
                 u16* __restrict__ Ol) {
    int bid = blockIdx.x;
    int loc = bid >> 3;
    int b = (bid & 7) * 8 + loc / 18;
    int rem = loc % 18;
    int h = rem / 9, qt = rem % 9;
    const int tid = threadIdx.x;
    __shared__ float Qs[32][68], Ks[32][68], Vs[32][68];
    __shared__ float Ps[32][36];
    int q0 = qt * 32;
    // stage Q: 512 float4
    for (int e = tid; e < 512; e += 256) {
        int r = e >> 4, d4 = (e & 15) * 4;
        *(float4*)&Qs[r][d4] =
            *(const float4*)&qkv[((size_t)(b * NT + q0 + r)) * 384 + h * 64 + d4];
    }
    float m = -INFINITY, l = 0.0f;
    float o[8];
    #pragma unroll
    for (int dd = 0; dd < 8; dd++) o[dd] = 0.0f;
    const int i = tid >> 3;     // q-row 0..31
    const int jg = tid & 7;     // lane group

    for (int kt = 0; kt < 9; kt++) {
        __syncthreads();        // prev PV done reading Ks/Vs; Qs ready (kt=0)
        int k0 = kt * 32;
        for (int e = tid; e < 512; e += 256) {
            int r = e >> 4, d4 = (e & 15) * 4;
            size_t rowb = ((size_t)(b * NT + k0 + r)) * 384 + h * 64;
            *(float4*)&Ks[r][d4] = *(const float4*)&qkv[rowb + 128 + d4];
            *(float4*)&Vs[r][d4] = *(const float4*)&qkv[rowb + 256 + d4];
        }
        __syncthreads();
        // ---- QK^T: this thread handles k-rows j = jg + 8*jj ----
        float s[4] = {0.f, 0.f, 0.f, 0.f};
        #pragma unroll
        for (int d4 = 0; d4 < 64; d4 += 4) {
            float4 q4 = *(float4*)&Qs[i][d4];
            #pragma unroll
            for (int jj = 0; jj < 4; jj++) {
                float4 k4 = *(float4*)&Ks[jg + 8 * jj][d4];
                s[jj] = fmaf(q4.x, k4.x, s[jj]);
                s[jj] = fmaf(q4.y, k4.y, s[jj]);
                s[jj] = fmaf(q4.z, k4.z, s[jj]);
                s[jj] = fmaf(q4.w, k4.w, s[jj]);
            }
        }
        #pragma unroll
        for (int jj = 0; jj < 4; jj++) s[jj] *= SCALE_;
        float tmax = fmaxf(fmaxf(s[0], s[1]), fmaxf(s[2], s[3]));
        #pragma unroll
        for (int off = 1; off < 8; off <<= 1) tmax = fmaxf(tmax, __shfl_xor(tmax, off));
        float mnew = fmaxf(m, tmax);
        float p[4], psum = 0.0f;
        #pragma unroll
        for (int jj = 0; jj < 4; jj++) { p[jj] = expf(s[jj] - mnew); psum += p[jj]; }
        #pragma unroll
        for (int off = 1; off < 8; off <<= 1) psum += __shfl_xor(psum, off);
        float alpha = expf(m - mnew);
        l = l * alpha + psum;
        m = mnew;
        #pragma unroll
        for (int dd = 0; dd < 8; dd++) o[dd] *= alpha;
        #pragma unroll
        for (int jj = 0; jj < 4; jj++) Ps[i][jg + 8 * jj] = p[jj];
        // Ps row i written & read by the same 8-lane group (same wave):
        // no barrier needed before PV.
        // ---- PV: columns jg*8 .. jg*8+7 ----
        #pragma unroll
        for (int j4 = 0; j4 < 32; j4 += 4) {
            float4 p4 = *(float4*)&Ps[i][j4];
            float pv[4] = {p4.x, p4.y, p4.z, p4.w};
            #pragma unroll
            for (int u = 0; u < 4; u++) {
                float pj = pv[u];
                float4 va = *(float4*)&Vs[j4 + u][jg * 8];
                float4 vb = *(float4*)&Vs[j4 + u][jg * 8 + 4];
                o[0] = fmaf(pj, va.x, o[0]); o[1] = fmaf(pj, va.y, o[1]);
                o[2] = fmaf(pj, va.z, o[2]); o[3] = fmaf(pj, va.w, o[3]);
                o[4] = fmaf(pj, vb.x, o[4]); o[5] = fmaf(pj, vb.y, o[5]);
                o[6] = fmaf(pj, vb.z, o[6]); o[7] = fmaf(pj, vb.w, o[7]);
            }
        }
    }
    float rl = 1.0f / l;
    ushort4 hv0, lv0, hv1, lv1;
    split_bf(o[0] * rl, hv0.x, lv0.x); split_bf(o[1] * rl, hv0.y, lv0.y);
    split_bf(o[2] * rl, hv0.z, lv0.z); split_bf(o[3] * rl, hv0.w, lv0.w);
    split_bf(o[4] * rl, hv1.x, lv1.x); split_bf(o[5] * rl, hv1.y, lv1.y);
    split_bf(o[6] * rl, hv1.z, lv1.z); split_bf(o[7] * rl, hv1.w, lv1.w);
    size_t oidx = ((size_t)(b * NT + q0 + i)) * 128 + h * 64 + jg * 8;
    *(ushort4*)&Oh[oidx] = hv0; *(ushort4*)&Oh[oidx + 4] = hv1;
    *(ushort4*)&Ol[oidx] = lv0; *(ushort4*)&Ol[oidx + 4] = lv1;
}

// ---------------- dots tile (self-normalizing) ----------------
__global__ __launch_bounds__(256)
void dots_tile(const float* __restrict__ G2, float* __restrict__ dots) {
    __shared__ float Sl[32][132];
    __shared__ float Cl[64][132];
    int b = blockIdx.y, jt = blockIdx.x;
    int tid = threadIdx.x;
    int j = tid & 63, sg = tid >> 6;
    const float* gb = G2 + (size_t)b * NT * 768;
    float acc[8], s2[8];
    #pragma unroll
    for (int s = 0; s < 8; s++) { acc[s] = 0.f; s2[s] = 0.f; }
    float c2 = 0.f;
    for (int kt = 0; kt < 6; kt++) {
        __syncthreads();
        #pragma unroll
        for (int i = 0; i < 4; i++) {
            int f = tid + i * 256; int r = f >> 5; int c = (f & 31) * 4;
            int sr = (r < 16) ? r : (r + 256);
            *(float4*)&Sl[r][c] = *(const float4*)&gb[(size_t)sr * 768 + kt * 128 + c];
        }
        #pragma unroll
        for (int i = 0; i < 8; i++) {
            int f = tid + i * 256; int r = f >> 5; int c = (f & 31) * 4;
            *(float4*)&Cl[r][c] = *(const float4*)&gb[(size_t)(16 + jt * 64 + r) * 768 + kt * 128 + c];
        }
        __syncthreads();
        for (int dd = 0; dd < 32; dd++) {
            float4 c4 = *(const float4*)&Cl[j][dd * 4];
            c2 += c4.x*c4.x + c4.y*c4.y + c4.z*c4.z + c4.w*c4.w;
            #pragma unroll
            for (int s = 0; s < 8; s++) {
                float4 s4 = *(const float4*)&Sl[sg * 8 + s][dd * 4];
                acc[s] += s4.x*c4.x + s4.y*c4.y + s4.z*c4.z + s4.w*c4.w;
                s2[s]  += s4.x*s4.x + s4.y*s4.y + s4.z*s4.z + s4.w*s4.w;
            }
        }
    }
    float cn = fmaxf(sqrtf(c2), 1e-12f);
    #pragma unroll
    for (int s = 0; s < 8; s++) {
        int si = sg * 8 + s;
        float v = acc[s] / (fmaxf(sqrtf(s2[s]), 1e-12f) * cn);
        dots[((size_t)(b * 32 + si)) * 256 + jt * 64 + j] = v;
    }
}

// ---------------- argmax over 256 candidates ----------------
__global__ __launch_bounds__(64)
void argmax_k(const float* __restrict__ dots, int* __restrict__ idx) {
    int r = blockIdx.x;
    const float* dr = dots + (size_t)r * 256;
    int lane = threadIdx.x;
    float bv = -1e30f; int bi = 0;
    #pragma unroll
    for (int i = 0; i < 4; i++) {
        int jj = i * 64 + lane;
        float v = dr[jj];
        if (v > bv) { bv = v; bi = jj; }
    }
    #pragma unroll
    for (int off = 32; off; off >>= 1) {
        float ov = __shfl_xor(bv, off); int oi = __shfl_xor(bi, off);
        if (ov > bv || (ov == bv && oi < bi)) { bv = ov; bi = oi; }
    }
    if (lane == 0) idx[r] = bi;
}

// ---------------- final output assembly ----------------
__global__ __launch_bounds__(256)
void out_assemble(const float* __restrict__ G2, const int* __restrict__ idx,
                  float* __restrict__ out) {
    size_t e = (size_t)blockIdx.x * 256 + threadIdx.x;
    int ww = (int)(e % 288); size_t r = e / 288;
    int hh_ = (int)(r % 256); r /= 256;
    int ch = (int)(r % 3); int b = (int)(r / 3);
    int wp = ww >> 4, px = ww & 15, hp = hh_ >> 4, py = hh_ & 15;
    int t = wp * 16 + hp;
    int srow;
    if (t < 16)       srow = 16 + idx[b * 32 + t];
    else if (t < 272) srow = t;
    else              srow = 16 + idx[b * 32 + 16 + (t - 272)];
    out[e] = G2[((size_t)b * NT + srow) * 768 + (py * 16 + px) * 3 + ch];
}

// ---------------- host launcher ----------------
extern "C" void kernel_launch(void* const* d_in, const int* in_sizes, int n_in,
                              void* d_out, int out_size, void* d_ws, size_t ws_size,
                              hipStream_t stream) {
    const float* img    = (const float*)d_in[0];
    const float* W_pe   = (const float*)d_in[1];
    const float* b_pe   = (const float*)d_in[2];
    const float* cls_l  = (const float*)d_in[3];
    const float* cls_r  = (const float*)d_in[4];
    const float* W_lin  = (const float*)d_in[5];
    const float* b_lin  = (const float*)d_in[6];
    const float* pos    = (const float*)d_in[7];
    const float* ln1_s  = (const float*)d_in[8];
    const float* ln1_b  = (const float*)d_in[9];
    const float* Wqkv   = (const float*)d_in[10];
    const float* Wo     = (const float*)d_in[11];
    const float* bo     = (const float*)d_in[12];
    const float* ln2_s  = (const float*)d_in[13];
    const float* ln2_b  = (const float*)d_in[14];
    const float* W1     = (const float*)d_in[15];
    const float* b1     = (const float*)d_in[16];
    const float* W2     = (const float*)d_in[17];
    const float* b2     = (const float*)d_in[18];
    const float* lng_s  = (const float*)d_in[19];
    const float* lng_b  = (const float*)d_in[20];
    const float* Wg     = (const float*)d_in[21];
    const float* bg     = (const float*)d_in[22];

    unsigned char* wsb = (unsigned char*)d_ws;
    // ---- layout (bytes); high-water 188,743,680 (R9 layout) ----
    const size_t XB = 75497472;                 // end of x
    const size_t XD = 150994944;                // D region
    float* x    = (float*)(wsb + 0);
    // B region
    u16*  wAll  = (u16*)(wsb + XB);             // 40MB layer weights (post-embed)
    u16*  xph   = (u16*)(wsb + XB);             // patches hi (embed phase)
    u16*  xpl   = (u16*)(wsb + XB + 25165824);  // patches lo
    float* g2   = (float*)(wsb + XB);           // head phase (56.6MB)
    u16*  wEh   = (u16*)(wsb + XB + 56623104);  // embed/head W slot
    u16*  wEl   = (u16*)(wsb + XB + 58195968);
    float2* stats2 = (float2*)(wsb + XB + 59768832);   // 8*18432 float2 = 1.18MB
    float* dotsb  = (float*)(wsb + XB + 60948480);     // 2MB
    float* clb    = (float*)(wsb + XB + 63045632);
    int*   idxb   = (int*)(wsb + XB + 63176704);
    // D region
    float* qkvb = (float*)(wsb + XD);           // 28.3MB
    u16*  hhb   = (u16*)(wsb + XD);             // aliases qkv (dead then)
    u16*  hlb   = (u16*)(wsb + XD + 9437184);
    u16*  ohb   = (u16*)(wsb + XD + 28311552);
    u16*  olb   = (u16*)(wsb + XD + 33030144);  // ends 188,743,680

    const int M = MROWS;   // 18432

    // ---- embed ----
    build_patches<<<49152, 256, 0, stream>>>(img, xph, xpl);
    convert_wT<<<dim3(32, 24), 256, 0, stream>>>(W_pe, wEh, wEl, 768, 1024);
    gemm_f32<1><<<dim3(16, 1), 256, 0, stream>>>(cls_l, W_lin, b_lin, clb, 16, 1024, 768);
    gemm_f32<1><<<dim3(16, 1), 256, 0, stream>>>(cls_r, W_lin, b_lin, clb + 16 * 1024, 16, 1024, 768);
    gemm_bf16x3<1, true, false, false, false><<<1024, 256, 0, stream>>>(
        xph, xpl, wEh, wEl, b_pe, x, nullptr, nullptr,
        nullptr, nullptr, 0, nullptr, nullptr, nullptr, 16384, 1024, 768, 8, 16);
    finish_embed_stats<<<M, 256, 0, stream>>>(clb, pos, x, stats2);
    bigconvert<<<10240, 256, 0, stream>>>(Wqkv, Wo, W1, W2, wAll);

    // ---- transformer layers (m-tiles = 144, mtq = 18) ----
    for (int i = 0; i < DEPTH; i++) {
        u16* lw = wAll + (size_t)i * 2097152;
        int ncb = (i == 0) ? 1 : 8;
        gemm_bf16x3<0, false, true, false, false><<<432, 256, 0, stream>>>(
            nullptr, nullptr, lw, lw + 393216, nullptr, qkvb, nullptr, nullptr,
            x, stats2, ncb, nullptr, ln1_s + i * 1024, ln1_b + i * 1024,
            M, 384, 1024, 3, 18);
        attn_kernel<<<1152, 256, 0, stream>>>(qkvb, ohb, olb);
        gemm_bf16x3<2, false, false, false, true><<<1152, 256, 0, stream>>>(
            ohb, olb, lw + 786432, lw + 917504, bo + i * 1024, x, nullptr, nullptr,
            nullptr, nullptr, 0, stats2, nullptr, nullptr, M, 1024, 128, 8, 18);
        gemm_bf16x3<3, false, true, false, false><<<288, 256, 0, stream>>>(
            nullptr, nullptr, lw + 1048576, lw + 1310720, b1 + i * 256, nullptr, hhb, hlb,
            x, stats2, 8, nullptr, ln2_s + i * 1024, ln2_b + i * 1024,
            M, 256, 1024, 2, 18);
        gemm_bf16x3<2, false, false, false, true><<<1152, 256, 0, stream>>>(
            hhb, hlb, lw + 1572864, lw + 1835008, b2 + i * 1024, x, nullptr, nullptr,
            nullptr, nullptr, 0, stats2, nullptr, nullptr, M, 1024, 256, 8, 18);
    }

    // ---- head ----
    convert_wT<<<dim3(24, 32), 256, 0, stream>>>(Wg, wEh, wEl, 1024, 768);
    gemm_bf16x3<1, false, true, true, false><<<864, 256, 0, stream>>>(
        nullptr, nullptr, wEh, wEl, bg, g2, nullptr, nullptr,
        x, stats2, 8, nullptr, lng_s, lng_b, M, 768, 1024, 6, 18);
    dots_tile<<<dim3(4, BB), 256, 0, stream>>>(g2, dotsb);
    argmax_k<<<2048, 64, 0, stream>>>(dotsb, idxb);
    out_assemble<<<55296, 256, 0, stream>>>(g2, idxb, (float*)d_out);
}

// Round 17
// 4025.749 us; speedup vs baseline: 1.0054x; 1.0054x over previous
//
#include <hip/hip_runtime.h>
#include <hip/hip_bf16.h>
#include <math.h>

// ---------------- problem constants ----------------
#define BB 64
#define CC 3
#define HH 256
#define WW 256
#define PP 16
#define DD 1024
#define DEPTH 10
#define HEADS 2
#define DHD 64
#define MLPD 256
#define INNER 128
#define NCLS 16
#define NT 288
#define PDIM 768
#define SCALE_ 0.125f
#define MROWS 18432          // BB*NT

typedef unsigned short u16;
typedef __attribute__((ext_vector_type(4))) int   i32x4;
typedef __attribute__((ext_vector_type(4))) float f32x4;

// ---------------- helpers ----------------
__device__ __forceinline__ float gelu_f(float x) {
    return 0.5f * x * (1.0f + erff(x * 0.70710678118654752f));
}

__device__ __forceinline__ u16 f2bf_rne(float x) {
    unsigned u = __float_as_uint(x);
    unsigned r = u + 0x7FFFu + ((u >> 16) & 1u);
    return (u16)(r >> 16);
}
__device__ __forceinline__ void split_bf(float x, u16& h, u16& l) {
    h = f2bf_rne(x);
    float fh = __uint_as_float(((unsigned)h) << 16);
    l = f2bf_rne(x - fh);
}

__device__ __forceinline__ void mfma_bf16(f32x4& acc, i32x4 a, i32x4 b) {
    asm("v_mfma_f32_16x16x32_bf16 %0, %1, %2, %0" : "+v"(acc) : "v"(a), "v"(b));
}

__device__ __forceinline__ void gload16(const void* g, void* l) {
    __builtin_amdgcn_global_load_lds(
        (const __attribute__((address_space(1))) void*)g,
        (__attribute__((address_space(3))) void*)l, 16, 0, 0);
}

__device__ __forceinline__ float block_sum_1024(float v, float* red) {
    #pragma unroll
    for (int off = 32; off; off >>= 1) v += __shfl_xor(v, off);
    __syncthreads();
    if ((threadIdx.x & 63) == 0) red[threadIdx.x >> 6] = v;
    __syncthreads();
    return red[0] + red[1] + red[2] + red[3];
}

// LN-transform 8 consecutive elems and split to packed hi/lo bf16x8
__device__ __forceinline__ void ln_split8(float4 xa, float4 xb, float mean, float rstd,
                                          float4 sa, float4 sb, float4 ba, float4 b_b,
                                          i32x4& hi, i32x4& lo) {
    float v0 = (xa.x - mean) * rstd * sa.x + ba.x;
    float v1 = (xa.y - mean) * rstd * sa.y + ba.y;
    float v2 = (xa.z - mean) * rstd * sa.z + ba.z;
    float v3 = (xa.w - mean) * rstd * sa.w + ba.w;
    float v4 = (xb.x - mean) * rstd * sb.x + b_b.x;
    float v5 = (xb.y - mean) * rstd * sb.y + b_b.y;
    float v6 = (xb.z - mean) * rstd * sb.z + b_b.z;
    float v7 = (xb.w - mean) * rstd * sb.w + b_b.w;
    u16 h0,h1,h2,h3,h4,h5,h6,h7, l0,l1,l2,l3,l4,l5,l6,l7;
    split_bf(v0,h0,l0); split_bf(v1,h1,l1); split_bf(v2,h2,l2); split_bf(v3,h3,l3);
    split_bf(v4,h4,l4); split_bf(v5,h5,l5); split_bf(v6,h6,l6); split_bf(v7,h7,l7);
    hi[0] = h0 | (h1 << 16); hi[1] = h2 | (h3 << 16);
    hi[2] = h4 | (h5 << 16); hi[3] = h6 | (h7 << 16);
    lo[0] = l0 | (l1 << 16); lo[1] = l2 | (l3 << 16);
    lo[2] = l4 | (l5 << 16); lo[3] = l6 | (l7 << 16);
}

// ---------------- patch gather (split bf16 hi/lo) ----------------
__global__ __launch_bounds__(256)
void build_patches(const float* __restrict__ img, u16* __restrict__ Xh,
                   u16* __restrict__ Xl) {
    size_t e = (size_t)blockIdx.x * 256 + threadIdx.x;  // 64*256*768
    int pd = (int)(e % 768); size_t r = e / 768;
    int t  = (int)(r % 256); int b = (int)(r / 256);
    int c = pd % 3; int pp = pd / 3; int px = pp & 15, py = pp >> 4;
    int wp = t & 15, hp = t >> 4;
    float v = img[(((size_t)b * 3 + c) * 256 + hp * 16 + py) * 256 + wp * 16 + px];
    u16 h, l; split_bf(v, h, l);
    Xh[e] = h; Xl[e] = l;
}

// ---------------- finish embed + layer-0 LN stats ----------------
__global__ __launch_bounds__(256)
void finish_embed_stats(const float* __restrict__ clb, const float* __restrict__ pos,
                        float* __restrict__ X, float2* __restrict__ stats) {
    __shared__ float red[4];
    int row = blockIdx.x; int t = row % NT;
    int tid = threadIdx.x;
    size_t xi = (size_t)row * 1024 + tid * 4;
    float4 p = *(const float4*)&pos[(size_t)t * 1024 + tid * 4];
    float4 v;
    if (t < 16)        v = *(const float4*)&clb[t * 1024 + tid * 4];
    else if (t >= 272) v = *(const float4*)&clb[(t - 256) * 1024 + tid * 4];
    else               v = *(const float4*)&X[xi];
    v.x += p.x; v.y += p.y; v.z += p.z; v.w += p.w;
    *(float4*)&X[xi] = v;
    float s = v.x + v.y + v.z + v.w;
    float q = v.x*v.x + v.y*v.y + v.z*v.z + v.w*v.w;
    float st = block_sum_1024(s, red);
    float qt = block_sum_1024(q, red);
    if (tid == 0) stats[row] = make_float2(st, qt);
}

// ---------------- weight convert: W f32 [K][N] -> hi/lo bf16 [N][K] -------
__global__ __launch_bounds__(256)
void convert_wT(const float* __restrict__ W, u16* __restrict__ Wh,
                u16* __restrict__ Wl, int K, int N) {
    __shared__ float t[32][33];
    int n0 = blockIdx.x * 32, k0 = blockIdx.y * 32;
    int c = threadIdx.x & 31, r8 = threadIdx.x >> 5;
    #pragma unroll
    for (int rr = r8; rr < 32; rr += 8)
        t[rr][c] = W[(size_t)(k0 + rr) * N + n0 + c];
    __syncthreads();
    #pragma unroll
    for (int rr = r8; rr < 32; rr += 8) {
        float v = t[c][rr];
        u16 h, l; split_bf(v, h, l);
        size_t o = (size_t)(n0 + rr) * K + k0 + c;
        Wh[o] = h; Wl[o] = l;
    }
}

// ---------------- all-layer weight convert (one launch) ----------------
__global__ __launch_bounds__(256)
void bigconvert(const float* __restrict__ Wqkv, const float* __restrict__ Wo,
                const float* __restrict__ W1, const float* __restrict__ W2,
                u16* __restrict__ wbase) {
    __shared__ float t[32][33];
    int bid = blockIdx.x;
    int layer = bid >> 10, tt = bid & 1023;
    u16* lb = wbase + (size_t)layer * 2097152;
    const float* src; u16* dh; u16* dl; int K, N, tloc;
    if (tt < 384)      { tloc = tt;       src = Wqkv + (size_t)layer*393216; K = 1024; N = 384;  dh = lb;           dl = lb + 393216; }
    else if (tt < 512) { tloc = tt - 384; src = Wo   + (size_t)layer*131072; K = 128;  N = 1024; dh = lb + 786432;  dl = lb + 917504; }
    else if (tt < 768) { tloc = tt - 512; src = W1   + (size_t)layer*262144; K = 1024; N = 256;  dh = lb + 1048576; dl = lb + 1310720; }
    else               { tloc = tt - 768; src = W2   + (size_t)layer*262144; K = 256;  N = 1024; dh = lb + 1572864; dl = lb + 1835008; }
    int tn = N >> 5;
    int n0 = (tloc % tn) * 32, k0 = (tloc / tn) * 32;
    int c = threadIdx.x & 31, r8 = threadIdx.x >> 5;
    #pragma unroll
    for (int rr = r8; rr < 32; rr += 8)
        t[rr][c] = src[(size_t)(k0 + rr) * N + n0 + c];
    __syncthreads();
    #pragma unroll
    for (int rr = r8; rr < 32; rr += 8) {
        float v = t[c][rr];
        u16 h, l; split_bf(v, h, l);
        size_t o = (size_t)(n0 + rr) * K + k0 + c;
        dh[o] = h; dl[o] = l;
    }
}

// ---------------- bf16x3 MFMA GEMM (R13 champion: gload_lds + vec epi) ----
#define SOFF(reg, tile) (((reg) * 8 + (tile)) * 512)
template<int EPI, bool ROWMAP, bool ALN, bool PERM, bool STATS>
__global__ __launch_bounds__(256, 2)
void gemm_bf16x3(const u16* __restrict__ Ah, const u16* __restrict__ Al,
                 const u16* __restrict__ Bh, const u16* __restrict__ Bl,
                 const float* __restrict__ bias, float* __restrict__ out,
                 u16* __restrict__ outH, u16* __restrict__ outL,
                 const float* __restrict__ xsrc,
                 const float2* __restrict__ statsIn, int ncb,
                 float2* __restrict__ statsOut,
                 const float* __restrict__ lns, const float* __restrict__ lnb,
                 int M, int Nn, int K, int NTn, int mtq) {
    __shared__ u16 smem[16384];            // (Ah,Al,Bh,Bl) x 8 tiles x 1KB = 32KB
    const int tid = threadIdx.x;
    const int w = tid >> 6, lane = tid & 63;
    const int wr = w >> 1, wc = w & 1;
    const int bid = blockIdx.x;
    const int loc = bid >> 3;
    const int n_t = loc % NTn;
    const int m_t = (bid & 7) * mtq + loc / NTn;
    const int m0 = m_t << 7, n0 = n_t << 7;
    const int lr = lane & 15, lg = lane >> 4;

    const u16* gp[8];
    int lb[8];
    {
        size_t b0 = (size_t)(n0 + (2 * w) * 16 + lr) * K + lg * 8;
        size_t b1 = (size_t)(n0 + (2 * w + 1) * 16 + lr) * K + lg * 8;
        gp[4] = Bh + b0; gp[5] = Bh + b1; gp[6] = Bl + b0; gp[7] = Bl + b1;
        if (!ALN) {
            size_t a0 = (size_t)(m0 + (2 * w) * 16 + lr) * K + lg * 8;
            size_t a1 = (size_t)(m0 + (2 * w + 1) * 16 + lr) * K + lg * 8;
            gp[0] = Ah + a0; gp[1] = Ah + a1; gp[2] = Al + a0; gp[3] = Al + a1;
        }
        lb[0] = SOFF(0, 2 * w); lb[1] = SOFF(0, 2 * w + 1);
        lb[2] = SOFF(1, 2 * w); lb[3] = SOFF(1, 2 * w + 1);
        lb[4] = SOFF(2, 2 * w); lb[5] = SOFF(2, 2 * w + 1);
        lb[6] = SOFF(3, 2 * w); lb[7] = SOFF(3, 2 * w + 1);
    }

    float mean0 = 0.f, rstd0 = 0.f, mean1 = 0.f, rstd1 = 0.f;
    const float* xr0 = nullptr; const float* xr1 = nullptr;
    if (ALN) {
        int r0 = m0 + (2 * w) * 16 + lr;
        int r1 = r0 + 16;
        float s0 = 0.f, q0 = 0.f, s1 = 0.f, q1 = 0.f;
        for (int cb = 0; cb < ncb; cb++) {
            float2 a = statsIn[cb * M + r0]; s0 += a.x; q0 += a.y;
            float2 b = statsIn[cb * M + r1]; s1 += b.x; q1 += b.y;
        }
        mean0 = s0 * (1.0f / 1024.0f);
        rstd0 = rsqrtf(q0 * (1.0f / 1024.0f) - mean0 * mean0 + 1e-5f);
        mean1 = s1 * (1.0f / 1024.0f);
        rstd1 = rsqrtf(q1 * (1.0f / 1024.0f) - mean1 * mean1 + 1e-5f);
        xr0 = xsrc + (size_t)r0 * K + lg * 8;
        xr1 = xsrc + (size_t)r1 * K + lg * 8;
    }

    f32x4 acc[4][4];
    #pragma unroll
    for (int i = 0; i < 4; i++)
        #pragma unroll
        for (int j = 0; j < 4; j++) acc[i][j] = f32x4{0.f, 0.f, 0.f, 0.f};

    const int nks = K >> 5;
    const int lo8 = lane * 8;
    for (int ks = 0; ks < nks; ks++) {
        // ---- stage step ks into the single buffer ----
        if (ALN) {
            #pragma unroll
            for (int q = 4; q < 8; q++) { gload16(gp[q], &smem[lb[q]]); gp[q] += 32; }
            const int kofs = ks * 32;
            float4 xa0 = *(const float4*)(xr0 + kofs), xb0 = *(const float4*)(xr0 + kofs + 4);
            float4 xa1 = *(const float4*)(xr1 + kofs), xb1 = *(const float4*)(xr1 + kofs + 4);
            const int kn = kofs + lg * 8;
            float4 sa = *(const float4*)(lns + kn), sb = *(const float4*)(lns + kn + 4);
            float4 ba = *(const float4*)(lnb + kn), b_b = *(const float4*)(lnb + kn + 4);
            i32x4 hi0, lo0, hi1, lo1;
            ln_split8(xa0, xb0, mean0, rstd0, sa, sb, ba, b_b, hi0, lo0);
            ln_split8(xa1, xb1, mean1, rstd1, sa, sb, ba, b_b, hi1, lo1);
            *(i32x4*)&smem[lb[0] + lane * 8] = hi0;
            *(i32x4*)&smem[lb[1] + lane * 8] = hi1;
            *(i32x4*)&smem[lb[2] + lane * 8] = lo0;
            *(i32x4*)&smem[lb[3] + lane * 8] = lo1;
        } else {
            #pragma unroll
            for (int q = 0; q < 8; q++) { gload16(gp[q], &smem[lb[q]]); gp[q] += 32; }
        }
        __syncthreads();
        // ---- compute ----
        i32x4 a_h[4], a_l[4], b_h[4], b_l[4];
        #pragma unroll
        for (int i = 0; i < 4; i++) {
            a_h[i] = *(const i32x4*)&smem[SOFF(0, wr * 4 + i) + lo8];
            a_l[i] = *(const i32x4*)&smem[SOFF(1, wr * 4 + i) + lo8];
            b_h[i] = *(const i32x4*)&smem[SOFF(2, wc * 4 + i) + lo8];
            b_l[i] = *(const i32x4*)&smem[SOFF(3, wc * 4 + i) + lo8];
        }
        #pragma unroll
        for (int i = 0; i < 4; i++)
            #pragma unroll
            for (int j = 0; j < 4; j++) {
                mfma_bf16(acc[i][j], a_h[i], b_h[j]);
                mfma_bf16(acc[i][j], a_h[i], b_l[j]);
                mfma_bf16(acc[i][j], a_l[i], b_h[j]);
            }
        __syncthreads();
    }

    // ---- vectorized epilogue: stage acc -> LDS (f32), float4 IO ----
    float* lds_f = (float*)smem;
    #pragma unroll
    for (int h = 0; h < 2; h++) {
        __syncthreads();
        if (wr == h) {
            #pragma unroll
            for (int i = 0; i < 4; i++)
                #pragma unroll
                for (int j = 0; j < 4; j++)
                    #pragma unroll
                    for (int r = 0; r < 4; r++)
                        lds_f[(i * 16 + lg * 4 + r) * 128 + wc * 64 + j * 16 + lr]
                            = acc[i][j][r];
        }
        __syncthreads();
        #pragma unroll
        for (int k = 0; k < 8; k++) {
            int f = k * 256 + tid;
            int rloc = f >> 5;
            int c4 = f & 31;
            int row = m0 + h * 64 + rloc;
            int col = n0 + c4 * 4;
            float4 v = *(float4*)&lds_f[rloc * 128 + c4 * 4];
            if (EPI >= 1) {
                float4 bv = *(const float4*)&bias[col];
                v.x += bv.x; v.y += bv.y; v.z += bv.z; v.w += bv.w;
            }
            int orow = row;
            if (ROWMAP) orow = row + 16 + 32 * (row >> 8);
            if (PERM) {
                int bi = row / 288; int t1 = row - bi * 288;
                int hp = t1 / 18; int wp = t1 - hp * 18;
                orow = bi * 288 + wp * 16 + hp;
            }
            size_t oidx = (size_t)orow * Nn + col;
            if (EPI == 3) {
                ushort4 hv, lv;
                float g0 = gelu_f(v.x), g1 = gelu_f(v.y);
                float g2 = gelu_f(v.z), g3 = gelu_f(v.w);
                split_bf(g0, hv.x, lv.x); split_bf(g1, hv.y, lv.y);
                split_bf(g2, hv.z, lv.z); split_bf(g3, hv.w, lv.w);
                *(ushort4*)&outH[oidx] = hv;
                *(ushort4*)&outL[oidx] = lv;
            } else if (EPI == 2) {
                float4 rv = *(float4*)&out[oidx];
                v.x += rv.x; v.y += rv.y; v.z += rv.z; v.w += rv.w;
                *(float4*)&out[oidx] = v;
                if (STATS) {
                    float s = v.x + v.y + v.z + v.w;
                    float q = v.x*v.x + v.y*v.y + v.z*v.z + v.w*v.w;
                    #pragma unroll
                    for (int off = 1; off < 32; off <<= 1) {
                        s += __shfl_xor(s, off);
                        q += __shfl_xor(q, off);
                    }
                    if ((tid & 31) == 0)
                        statsOut[n_t * M + row] = make_float2(s, q);
                }
            } else {
                *(float4*)&out[oidx] = v;
            }
        }
    }
}

// ---------------- f32 GEMM (tiny cls matmuls, M=16) ----------
template<int EPI>
__global__ __launch_bounds__(256)
void gemm_f32(const float* __restrict__ A, const float* __restrict__ Wt,
              const float* __restrict__ bias, float* __restrict__ Cout,
              int M, int Nn, int K) {
    __shared__ float As[16][132];
    __shared__ float Bs[16][68];
    const int tid = threadIdx.x;
    const int m0 = blockIdx.y * 128;
    const int n0 = blockIdx.x * 64;
    const int ty = tid >> 4, tx = tid & 15;
    float acc[8][4];
    #pragma unroll
    for (int r = 0; r < 8; r++)
        #pragma unroll
        for (int c = 0; c < 4; c++) acc[r][c] = 0.0f;
    const int af4 = tid & 3;
    const int arow0 = tid >> 2;
    const int bcol = tid & 63, brow0 = tid >> 6;
    for (int k0 = 0; k0 < K; k0 += 16) {
        #pragma unroll
        for (int rr = 0; rr < 2; rr++) {
            int row = arow0 + rr * 64;
            int gm = m0 + row;
            float4 v = make_float4(0.f, 0.f, 0.f, 0.f);
            if (gm < M) v = *(const float4*)&A[(size_t)gm * K + k0 + af4 * 4];
            As[af4 * 4 + 0][row] = v.x; As[af4 * 4 + 1][row] = v.y;
            As[af4 * 4 + 2][row] = v.z; As[af4 * 4 + 3][row] = v.w;
        }
        #pragma unroll
        for (int rr = 0; rr < 4; rr++) {
            int krow = brow0 + rr * 4;
            Bs[krow][bcol] = Wt[(size_t)(k0 + krow) * Nn + n0 + bcol];
        }
        __syncthreads();
        #pragma unroll
        for (int kk = 0; kk < 16; kk++) {
            float4 a0 = *(const float4*)&As[kk][ty * 8];
            float4 a1 = *(const float4*)&As[kk][ty * 8 + 4];
            float4 b0 = *(const float4*)&Bs[kk][tx * 4];
            float ar[8] = {a0.x, a0.y, a0.z, a0.w, a1.x, a1.y, a1.z, a1.w};
            float bc[4] = {b0.x, b0.y, b0.z, b0.w};
            #pragma unroll
            for (int r = 0; r < 8; r++)
                #pragma unroll
                for (int c = 0; c < 4; c++)
                    acc[r][c] = fmaf(ar[r], bc[c], acc[r][c]);
        }
        __syncthreads();
    }
    float4 bv = make_float4(0.f, 0.f, 0.f, 0.f);
    if (EPI >= 1) bv = *(const float4*)&bias[n0 + tx * 4];
    #pragma unroll
    for (int r = 0; r < 8; r++) {
        int gm = m0 + ty * 8 + r;
        if (gm >= M) continue;
        float4 v = make_float4(acc[r][0], acc[r][1], acc[r][2], acc[r][3]);
        if (EPI >= 1) { v.x += bv.x; v.y += bv.y; v.z += bv.z; v.w += bv.w; }
        *(float4*)&Cout[(size_t)gm * Nn + n0 + tx * 4] = v;
    }
}

// ---------------- attention (flash-style, f32, float4 LDS) ----------------
// LDS-throughput rewrite: padded-68 rows (16B aligned), float4 staging and
// fragment reads (4x fewer LDS instrs, 2x bytes/cycle), conflict-free K-row
// mapping j = jg + 8*jj (bank starts 4*jg+d -> full 32-bank tiling), float4
// P/V reads, ushort4 stores. FMA order identical to scalar version.
__global__ __launch_bounds__(256)
void attn_kernel(const float* __restrict__ qkv, u16* __restrict__ Oh,
                 u16* __restrict__ Ol) {
    int bid = blockIdx.x;
    int loc = bid >> 3;
    int b = (bid & 7) * 8 + loc / 18;
    int rem = loc % 18;
    int h = rem / 9, qt = rem % 9;
    const int tid = threadIdx.x;
    __shared__ float Qs[32][68], Ks[32][68], Vs[32][68];
    __shared__ float Ps[32][36];
    int q0 = qt * 32;
    // stage Q: 512 float4
    for (int e = tid; e < 512; e += 256) {
        int r = e >> 4, d4 = (e & 15) * 4;
        *(float4*)&Qs[r][d4] =
            *(const float4*)&qkv[((size_t)(b * NT + q0 + r)) * 384 + h * 64 + d4];
    }
    float m = -INFINITY, l = 0.0f;
    float o[8];
    #pragma unroll
    for (int dd = 0; dd < 8; dd++) o[dd] = 0.0f;
    const int i = tid >> 3;     // q-row 0..31
    const int jg = tid & 7;     // lane group

    for (int kt = 0; kt < 9; kt++) {
        __syncthreads();        // prev PV done reading Ks/Vs; Qs ready (kt=0)
        int k0 = kt * 32;
        for (int e = tid; e < 512; e += 256) {
            int r = e >> 4, d4 = (e & 15) * 4;
            size_t rowb = ((size_t)(b * NT + k0 + r)) * 384 + h * 64;
            *(float4*)&Ks[r][d4] = *(const float4*)&qkv[rowb + 128 + d4];
            *(float4*)&Vs[r][d4] = *(const float4*)&qkv[rowb + 256 + d4];
        }
        __syncthreads();
        // ---- QK^T: this thread handles k-rows j = jg + 8*jj ----
        float s[4] = {0.f, 0.f, 0.f, 0.f};
        #pragma unroll
        for (int d4 = 0; d4 < 64; d4 += 4) {
            float4 q4 = *(float4*)&Qs[i][d4];
            #pragma unroll
            for (int jj = 0; jj < 4; jj++) {
                float4 k4 = *(float4*)&Ks[jg + 8 * jj][d4];
                s[jj] = fmaf(q4.x, k4.x, s[jj]);
                s[jj] = fmaf(q4.y, k4.y, s[jj]);
                s[jj] = fmaf(q4.z, k4.z, s[jj]);
                s[jj] = fmaf(q4.w, k4.w, s[jj]);
            }
        }
        #pragma unroll
        for (int jj = 0; jj < 4; jj++) s[jj] *= SCALE_;
        float tmax = fmaxf(fmaxf(s[0], s[1]), fmaxf(s[2], s[3]));
        #pragma unroll
        for (int off = 1; off < 8; off <<= 1) tmax = fmaxf(tmax, __shfl_xor(tmax, off));
        float mnew = fmaxf(m, tmax);
        float p[4], psum = 0.0f;
        #pragma unroll
        for (int jj = 0; jj < 4; jj++) { p[jj] = expf(s[jj] - mnew); psum += p[jj]; }
        #pragma unroll
        for (int off = 1; off < 8; off <<= 1) psum += __shfl_xor(psum, off);
        float alpha = expf(m - mnew);
        l = l * alpha + psum;
        m = mnew;
        #pragma unroll
        for (int dd = 0; dd < 8; dd++) o[dd] *= alpha;
        #pragma unroll
        for (int jj = 0; jj < 4; jj++) Ps[i][jg + 8 * jj] = p[jj];
        // Ps row i written & read by the same 8-lane group (same wave):
        // no barrier needed before PV.
        // ---- PV: columns jg*8 .. jg*8+7 ----
        #pragma unroll
        for (int j4 = 0; j4 < 32; j4 += 4) {
            float4 p4 = *(float4*)&Ps[i][j4];
            float pv[4] = {p4.x, p4.y, p4.z, p4.w};
            #pragma unroll
            for (int u = 0; u < 4; u++) {
                float pj = pv[u];
                float4 va = *(float4*)&Vs[j4 + u][jg * 8];
                float4 vb = *(float4*)&Vs[j4 + u][jg * 8 + 4];
                o[0] = fmaf(pj, va.x, o[0]); o[1] = fmaf(pj, va.y, o[1]);
                o[2] = fmaf(pj, va.z, o[2]); o[3] = fmaf(pj, va.w, o[3]);
                o[4] = fmaf(pj, vb.x, o[4]); o[5] = fmaf(pj, vb.y, o[5]);
                o[6] = fmaf(pj, vb.z, o[6]); o[7] = fmaf(pj, vb.w, o[7]);
            }
        }
    }
    float rl = 1.0f / l;
    ushort4 hv0, lv0, hv1, lv1;
    split_bf(o[0] * rl, hv0.x, lv0.x); split_bf(o[1] * rl, hv0.y, lv0.y);
    split_bf(o[2] * rl, hv0.z, lv0.z); split_bf(o[3] * rl, hv0.w, lv0.w);
    split_bf(o[4] * rl, hv1.x, lv1.x); split_bf(o[5] * rl, hv1.y, lv1.y);
    split_bf(o[6] * rl, hv1.z, lv1.z); split_bf(o[7] * rl, hv1.w, lv1.w);
    size_t oidx = ((size_t)(b * NT + q0 + i)) * 128 + h * 64 + jg * 8;
    *(ushort4*)&Oh[oidx] = hv0; *(ushort4*)&Oh[oidx + 4] = hv1;
    *(ushort4*)&Ol[oidx] = lv0; *(ushort4*)&Ol[oidx + 4] = lv1;
}

// ---------------- dots tile (self-normalizing) ----------------
__global__ __launch_bounds__(256)
void dots_tile(const float* __restrict__ G2, float* __restrict__ dots) {
    __shared__ float Sl[32][132];
    __shared__ float Cl[64][132];
    int b = blockIdx.y, jt = blockIdx.x;
    int tid = threadIdx.x;
    int j = tid & 63, sg = tid >> 6;
    const float* gb = G2 + (size_t)b * NT * 768;
    float acc[8], s2[8];
    #pragma unroll
    for (int s = 0; s < 8; s++) { acc[s] = 0.f; s2[s] = 0.f; }
    float c2 = 0.f;
    for (int kt = 0; kt < 6; kt++) {
        __syncthreads();
        #pragma unroll
        for (int i = 0; i < 4; i++) {
            int f = tid + i * 256; int r = f >> 5; int c = (f & 31) * 4;
            int sr = (r < 16) ? r : (r + 256);
            *(float4*)&Sl[r][c] = *(const float4*)&gb[(size_t)sr * 768 + kt * 128 + c];
        }
        #pragma unroll
        for (int i = 0; i < 8; i++) {
            int f = tid + i * 256; int r = f >> 5; int c = (f & 31) * 4;
            *(float4*)&Cl[r][c] = *(const float4*)&gb[(size_t)(16 + jt * 64 + r) * 768 + kt * 128 + c];
        }
        __syncthreads();
        for (int dd = 0; dd < 32; dd++) {
            float4 c4 = *(const float4*)&Cl[j][dd * 4];
            c2 += c4.x*c4.x + c4.y*c4.y + c4.z*c4.z + c4.w*c4.w;
            #pragma unroll
            for (int s = 0; s < 8; s++) {
                float4 s4 = *(const float4*)&Sl[sg * 8 + s][dd * 4];
                acc[s] += s4.x*c4.x + s4.y*c4.y + s4.z*c4.z + s4.w*c4.w;
                s2[s]  += s4.x*s4.x + s4.y*s4.y + s4.z*s4.z + s4.w*s4.w;
            }
        }
    }
    float cn = fmaxf(sqrtf(c2), 1e-12f);
    #pragma unroll
    for (int s = 0; s < 8; s++) {
        int si = sg * 8 + s;
        float v = acc[s] / (fmaxf(sqrtf(s2[s]), 1e-12f) * cn);
        dots[((size_t)(b * 32 + si)) * 256 + jt * 64 + j] = v;
    }
}

// ---------------- argmax over 256 candidates ----------------
__global__ __launch_bounds__(64)
void argmax_k(const float* __restrict__ dots, int* __restrict__ idx) {
    int r = blockIdx.x;
    const float* dr = dots + (size_t)r * 256;
    int lane = threadIdx.x;
    float bv = -1e30f; int bi = 0;
    #pragma unroll
    for (int i = 0; i < 4; i++) {
        int jj = i * 64 + lane;
        float v = dr[jj];
        if (v > bv) { bv = v; bi = jj; }
    }
    #pragma unroll
    for (int off = 32; off; off >>= 1) {
        float ov = __shfl_xor(bv, off); int oi = __shfl_xor(bi, off);
        if (ov > bv || (ov == bv && oi < bi)) { bv = ov; bi = oi; }
    }
    if (lane == 0) idx[r] = bi;
}

// ---------------- final output assembly ----------------
__global__ __launch_bounds__(256)
void out_assemble(const float* __restrict__ G2, const int* __restrict__ idx,
                  float* __restrict__ out) {
    size_t e = (size_t)blockIdx.x * 256 + threadIdx.x;
    int ww = (int)(e % 288); size_t r = e / 288;
    int hh_ = (int)(r % 256); r /= 256;
    int ch = (int)(r % 3); int b = (int)(r / 3);
    int wp = ww >> 4, px = ww & 15, hp = hh_ >> 4, py = hh_ & 15;
    int t = wp * 16 + hp;
    int srow;
    if (t < 16)       srow = 16 + idx[b * 32 + t];
    else if (t < 272) srow = t;
    else              srow = 16 + idx[b * 32 + 16 + (t - 272)];
    out[e] = G2[((size_t)b * NT + srow) * 768 + (py * 16 + px) * 3 + ch];
}

// ---------------- host launcher ----------------
extern "C" void kernel_launch(void* const* d_in, const int* in_sizes, int n_in,
                              void* d_out, int out_size, void* d_ws, size_t ws_size,
                              hipStream_t stream) {
    const float* img    = (const float*)d_in[0];
    const float* W_pe   = (const float*)d_in[1];
    const float* b_pe   = (const float*)d_in[2];
    const float* cls_l  = (const float*)d_in[3];
    const float* cls_r  = (const float*)d_in[4];
    const float* W_lin  = (const float*)d_in[5];
    const float* b_lin  = (const float*)d_in[6];
    const float* pos    = (const float*)d_in[7];
    const float* ln1_s  = (const float*)d_in[8];
    const float* ln1_b  = (const float*)d_in[9];
    const float* Wqkv   = (const float*)d_in[10];
    const float* Wo     = (const float*)d_in[11];
    const float* bo     = (const float*)d_in[12];
    const float* ln2_s  = (const float*)d_in[13];
    const float* ln2_b  = (const float*)d_in[14];
    const float* W1     = (const float*)d_in[15];
    const float* b1     = (const float*)d_in[16];
    const float* W2     = (const float*)d_in[17];
    const float* b2     = (const float*)d_in[18];
    const float* lng_s  = (const float*)d_in[19];
    const float* lng_b  = (const float*)d_in[20];
    const float* Wg     = (const float*)d_in[21];
    const float* bg     = (const float*)d_in[22];

    unsigned char* wsb = (unsigned char*)d_ws;
    // ---- layout (bytes); high-water 188,743,680 (R9 layout) ----
    const size_t XB = 75497472;                 // end of x
    const size_t XD = 150994944;                // D region
    float* x    = (float*)(wsb + 0);
    // B region
    u16*  wAll  = (u16*)(wsb + XB);             // 40MB layer weights (post-embed)
    u16*  xph   = (u16*)(wsb + XB);             // patches hi (embed phase)
    u16*  xpl   = (u16*)(wsb + XB + 25165824);  // patches lo
    float* g2   = (float*)(wsb + XB);           // head phase (56.6MB)
    u16*  wEh   = (u16*)(wsb + XB + 56623104);  // embed/head W slot
    u16*  wEl   = (u16*)(wsb + XB + 58195968);
    float2* stats2 = (float2*)(wsb + XB + 59768832);   // 8*18432 float2 = 1.18MB
    float* dotsb  = (float*)(wsb + XB + 60948480);     // 2MB
    float* clb    = (float*)(wsb + XB + 63045632);
    int*   idxb   = (int*)(wsb + XB + 63176704);
    // D region
    float* qkvb = (float*)(wsb + XD);           // 28.3MB
    u16*  hhb   = (u16*)(wsb + XD);             // aliases qkv (dead then)
    u16*  hlb   = (u16*)(wsb + XD + 9437184);
    u16*  ohb   = (u16*)(wsb + XD + 28311552);
    u16*  olb   = (u16*)(wsb + XD + 33030144);  // ends 188,743,680

    const int M = MROWS;   // 18432

    // ---- embed ----
    build_patches<<<49152, 256, 0, stream>>>(img, xph, xpl);
    convert_wT<<<dim3(32, 24), 256, 0, stream>>>(W_pe, wEh, wEl, 768, 1024);
    gemm_f32<1><<<dim3(16, 1), 256, 0, stream>>>(cls_l, W_lin, b_lin, clb, 16, 1024, 768);
    gemm_f32<1><<<dim3(16, 1), 256, 0, stream>>>(cls_r, W_lin, b_lin, clb + 16 * 1024, 16, 1024, 768);
    gemm_bf16x3<1, true, false, false, false><<<1024, 256, 0, stream>>>(
        xph, xpl, wEh, wEl, b_pe, x, nullptr, nullptr,
        nullptr, nullptr, 0, nullptr, nullptr, nullptr, 16384, 1024, 768, 8, 16);
    finish_embed_stats<<<M, 256, 0, stream>>>(clb, pos, x, stats2);
    bigconvert<<<10240, 256, 0, stream>>>(Wqkv, Wo, W1, W2, wAll);

    // ---- transformer layers (m-tiles = 144, mtq = 18) ----
    for (int i = 0; i < DEPTH; i++) {
        u16* lw = wAll + (size_t)i * 2097152;
        int ncb = (i == 0) ? 1 : 8;
        gemm_bf16x3<0, false, true, false, false><<<432, 256, 0, stream>>>(
            nullptr, nullptr, lw, lw + 393216, nullptr, qkvb, nullptr, nullptr,
            x, stats2, ncb, nullptr, ln1_s + i * 1024, ln1_b + i * 1024,
            M, 384, 1024, 3, 18);
        attn_kernel<<<1152, 256, 0, stream>>>(qkvb, ohb, olb);
        gemm_bf16x3<2, false, false, false, true><<<1152, 256, 0, stream>>>(
            ohb, olb, lw + 786432, lw + 917504, bo + i * 1024, x, nullptr, nullptr,
            nullptr, nullptr, 0, stats2, nullptr, nullptr, M, 1024, 128, 8, 18);
        gemm_bf16x3<3, false, true, false, false><<<288, 256, 0, stream>>>(
            nullptr, nullptr, lw + 1048576, lw + 1310720, b1 + i * 256, nullptr, hhb, hlb,
            x, stats2, 8, nullptr, ln2_s + i * 1024, ln2_b + i * 1024,
            M, 256, 1024, 2, 18);
        gemm_bf16x3<2, false, false, false, true><<<1152, 256, 0, stream>>>(
            hhb, hlb, lw + 1572864, lw + 1835008, b2 + i * 1024, x, nullptr, nullptr,
            nullptr, nullptr, 0, stats2, nullptr, nullptr, M, 1024, 256, 8, 18);
    }

    // ---- head ----
    convert_wT<<<dim3(24, 32), 256, 0, stream>>>(Wg, wEh, wEl, 1024, 768);
    gemm_bf16x3<1, false, true, true, false><<<864, 256, 0, stream>>>(
        nullptr, nullptr, wEh, wEl, bg, g2, nullptr, nullptr,
        x, stats2, 8, nullptr, lng_s, lng_b, M, 768, 1024, 6, 18);
    dots_tile<<<dim3(4, BB), 256, 0, stream>>>(g2, dotsb);
    argmax_k<<<2048, 64, 0, stream>>>(dotsb, idxb);
    out_assemble<<<55296, 256, 0, stream>>>(g2, idxb, (float*)d_out);
}